// Round 15
// baseline (2528.554 us; speedup 1.0000x reference)
//
#include <hip/hip_runtime.h>
#include <hip/hip_bf16.h>
#include <math.h>

#define LOG2PI 1.8378770664093453f

// Problem dims
constexpr int Bb = 16, Nn = 512, Tt = 16;
constexpr int dL = 128, dM = 256, dE = 32, Kt = 18;
constexpr int P = Bb * Nn;          // 8192 particles
constexpr int BLK = 16;             // particles per mega-block (2 blocks/CU)
// LDS row strides (in elements)
constexpr int LDA = 520;            // actA: 512 cols (H1|HR, later E1)
constexpr int LDB = 264;            // actB: 256 cols (H2)
constexpr int LDE = 136;            // e2/znew: 128 cols
constexpr int LDZX = 132;           // zls exchange (f32)
constexpr int LDR = 40;             // remb: 32 cols

typedef __attribute__((ext_vector_type(8))) _Float16 f16x8;
typedef __attribute__((ext_vector_type(4))) float f32x4;

__device__ __forceinline__ float siluf(float x) { return x / (1.f + expf(-x)); }
__device__ __forceinline__ float softplusf(float x) {
    return (x > 20.f) ? x : log1pf(expf(x));
}
__device__ __forceinline__ short f2h(float x) {
    _Float16 h = (_Float16)x;
    short s;
    __builtin_memcpy(&s, &h, 2);
    return s;
}
__device__ __forceinline__ float h2f(short s) {
    _Float16 h;
    __builtin_memcpy(&h, &s, 2);
    return (float)h;
}
__device__ __forceinline__ void split2(float x, short& hi, short& lo) {
    hi = f2h(x);
    lo = f2h(x - h2f(hi));
}
__device__ __forceinline__ f32x4 mfma16(f16x8 a, f16x8 b, f32x4 c) {
    return __builtin_amdgcn_mfma_f32_16x16x32_f16(a, b, c, 0, 0, 0);
}

// ---------------------------------------------------------------------------
// single-m-frag helpers (wave owns rows 0..15 of the block + NF n-frags)
// ---------------------------------------------------------------------------
template<int NF>
__device__ __forceinline__ void mfma_bn1(
    f16x8 ah, f16x8 al,
    const short* __restrict__ Whi, const short* __restrict__ Wlo,
    int Kw, int k0, int n0, int lr, int lk, f32x4 (&acc)[NF])
{
    #pragma unroll
    for (int nf = 0; nf < NF; nf++) {
        size_t bo = (size_t)(n0 + nf * 16 + lr) * Kw + k0 + lk;
        f16x8 bh = *reinterpret_cast<const f16x8*>(Whi + bo);
        f16x8 bl = *reinterpret_cast<const f16x8*>(Wlo + bo);
        acc[nf] = mfma16(ah, bh, acc[nf]);
        acc[nf] = mfma16(ah, bl, acc[nf]);
        acc[nf] = mfma16(al, bh, acc[nf]);
    }
}

// GEMM k-range, A from LDS split planes (ldA=0 -> broadcast row, e.g. h)
template<int NF, int KB, int KE, int KW>
__device__ __forceinline__ void gemm_lds1(
    const short* lAhi, const short* lAlo, int ldA, int akoff,
    const short* __restrict__ Whi, const short* __restrict__ Wlo,
    int n0, int lr, int lk, f32x4 (&acc)[NF])
{
    #pragma unroll 2
    for (int k0 = KB; k0 < KE; k0 += 32) {
        int ao = lr * ldA + (k0 - akoff) + lk;
        f16x8 ah = *reinterpret_cast<const f16x8*>(lAhi + ao);
        f16x8 al = *reinterpret_cast<const f16x8*>(lAlo + ao);
        mfma_bn1<NF>(ah, al, Whi, Wlo, KW, k0, n0, lr, lk, acc);
    }
}

// silu + split + store C-frags to LDS split buffer (rows l4+r)
template<int NF>
__device__ __forceinline__ void epi_silu1(
    f32x4 (&acc)[NF], const float* biasw,
    short* outHi, short* outLo, int ldOut, int outBase, int lr, int l4)
{
    #pragma unroll
    for (int nf = 0; nf < NF; nf++) {
        float bv = biasw[nf * 16 + lr];
        #pragma unroll
        for (int r = 0; r < 4; r++) {
            int row = l4 + r;
            int col = outBase + nf * 16 + lr;
            float sv = siluf(acc[nf][r] + bv);
            short hi, lo;
            split2(sv, hi, lo);
            outHi[row * ldOut + col] = hi;
            outLo[row * ldOut + col] = lo;
        }
    }
}

struct SMem {
    short actAhi[BLK * LDA], actAlo[BLK * LDA];
    short actBhi[BLK * LDB], actBlo[BLK * LDB];
    short e2hi[BLK * LDE], e2lo[BLK * LDE];    // z_new split, then E2
    short hhhi[256], hhlo[256];
    short rembhi[BLK * LDR], remblo[BLK * LDR];
    float zlsx[BLK * LDZX];
    float peL[256];
    float probs[BLK * 8];
    float rlogL[BLK * 8];
    float lqp[4 * BLK];
};

// ---------------------------------------------------------------------------
// MEGA: per-step fused per-particle chain. 512 blocks x 512 thr (8 waves),
// 16 particles per block, ~73 KB LDS -> 2 blocks/CU (independent barrier
// domains overlap phases). Wave owns 1 m-frag (rows 0-15) + 1 n-slice.
// ---------------------------------------------------------------------------
__global__ __launch_bounds__(512) void mega(
    const float* __restrict__ zc, const float* __restrict__ rl,
    const float* __restrict__ h_t, const float* __restrict__ pe_emb,
    const float* __restrict__ eps_t, const float* __restrict__ obs_t,
    const short* __restrict__ w_l1h, const short* __restrict__ w_l1l,
    const short* __restrict__ w_pz2h, const short* __restrict__ w_pz2l,
    const short* __restrict__ w_pz3h, const short* __restrict__ w_pz3l,
    const short* __restrict__ w_oe1h, const short* __restrict__ w_oe1l,
    const short* __restrict__ w_oe2h, const short* __restrict__ w_oe2l,
    const float* __restrict__ pz_b1, const float* __restrict__ pr_b1,
    const float* __restrict__ pz_b2, const float* __restrict__ pz_b3,
    const float* __restrict__ oe_b1, const float* __restrict__ oe_b2,
    const float* __restrict__ pr_w2, const float* __restrict__ pr_b2,
    const float* __restrict__ oe_w3, const float* __restrict__ oe_b3,
    const float* __restrict__ los,
    float* __restrict__ log_w,
    short* __restrict__ vthi, short* __restrict__ vtlo)
{
    __shared__ SMem sm;
    const int tid = threadIdx.x;
    const int wv = tid >> 6, l = tid & 63;
    const int lr = l & 15, lk = (l >> 4) * 8, l4 = (l >> 4) * 4;
    const int p0 = blockIdx.x * BLK;
    const int b = p0 >> 9;
    const int i0 = p0 & 511;

    // ---- P0: h broadcast, pe_emb, regime probs, vt pad zero ----
    {
        if (tid < 256) {
            const float* hb = h_t + b * dM;
            short hi, lo;
            split2(hb[tid], hi, lo);
            sm.hhhi[tid] = hi; sm.hhlo[tid] = lo;
            sm.peL[tid] = pe_emb[tid];
        } else if (tid < 384) {
            // vt pad cols 136-143 zero (16 rows x 8 cols = 128 items)
            int q = tid - 256;
            int pp = q >> 3, cc = q & 7;
            vthi[((size_t)b * 144 + 136 + cc) * 512 + i0 + pp] = 0;
            vtlo[((size_t)b * 144 + 136 + cc) * 512 + i0 + pp] = 0;
        }
        if (tid < BLK) {
            int p = tid;
            float v[Kt], m = -1e30f;
            #pragma unroll
            for (int k = 0; k < Kt; k++) {
                v[k] = rl[(size_t)(p0 + p) * Kt + k];
                m = fmaxf(m, v[k]);
            }
            float denom = 0.f;
            #pragma unroll
            for (int k = 0; k < Kt; k++) denom += expf(v[k] - m);
            #pragma unroll
            for (int k = 0; k < 8; k++)
                sm.probs[p * 8 + k] = expf(v[k] - m) / denom;
        }
    }
    __syncthreads();
    // remb = probs @ pe_emb[:8] — 512 items, one per thread
    {
        int p = tid >> 5, d = tid & 31;
        float acc = 0.f;
        #pragma unroll
        for (int kk = 0; kk < 8; kk++)
            acc = fmaf(sm.probs[p * 8 + kk], sm.peL[kk * 32 + d], acc);
        short hi, lo;
        split2(acc, hi, lo);
        sm.rembhi[p * LDR + d] = hi;
        sm.remblo[p * LDR + d] = lo;
    }
    __syncthreads();

    // ---- P1: layer1 [H1|HR] = silu(X @ [pz_w1|pr_w1]); X composed on the fly
    {
        f32x4 acc1[4];
        #pragma unroll
        for (int nf = 0; nf < 4; nf++) acc1[nf] = f32x4{0.f, 0.f, 0.f, 0.f};
        int n0 = wv * 64;
        // k 0..255: h (broadcast rows)
        gemm_lds1<4, 0, 256, 416>(sm.hhhi, sm.hhlo, 0, 0, w_l1h, w_l1l, n0, lr, lk, acc1);
        // k 256..383: z carry from global f32, split on the fly
        #pragma unroll 2
        for (int k0 = 256; k0 < 384; k0 += 32) {
            f16x8 ah, al;
            const float* zr = zc + (size_t)(p0 + lr) * dL + (k0 - 256) + lk;
            #pragma unroll
            for (int j = 0; j < 8; j++) {
                float zv = zr[j];
                _Float16 h = (_Float16)zv;
                ah[j] = h;
                al[j] = (_Float16)(zv - (float)h);
            }
            mfma_bn1<4>(ah, al, w_l1h, w_l1l, 416, k0, n0, lr, lk, acc1);
        }
        // k 384..415: remb
        gemm_lds1<4, 384, 416, 416>(sm.rembhi, sm.remblo, LDR, 384, w_l1h, w_l1l, n0, lr, lk, acc1);
        const float* biasw = (n0 < 256) ? (pz_b1 + n0) : (pr_b1 + (n0 - 256));
        epi_silu1<4>(acc1, biasw, sm.actAhi, sm.actAlo, LDA, n0, lr, l4);
    }
    __syncthreads();

    // ---- P2: H2 = silu(H1 @ pz_w2) ----
    {
        f32x4 acc2[2];
        acc2[0] = f32x4{0.f, 0.f, 0.f, 0.f};
        acc2[1] = f32x4{0.f, 0.f, 0.f, 0.f};
        int n0 = wv * 32;
        gemm_lds1<2, 0, 256, 256>(sm.actAhi, sm.actAlo, LDA, 0, w_pz2h, w_pz2l, n0, lr, lk, acc2);
        epi_silu1<2>(acc2, pz_b2 + n0, sm.actBhi, sm.actBlo, LDB, n0, lr, l4);
    }
    __syncthreads();

    // ---- P3: ZP = H2 @ pz_w3 (raw); z_new, log_q ----
    {
        f32x4 acc3[2];
        acc3[0] = f32x4{0.f, 0.f, 0.f, 0.f};
        acc3[1] = f32x4{0.f, 0.f, 0.f, 0.f};
        int n0 = wv * 32;
        gemm_lds1<2, 0, 256, 256>(sm.actBhi, sm.actBlo, LDB, 0, w_pz3h, w_pz3l, n0, lr, lk, acc3);
        if (wv >= 4) {   // z_log_std cols 128..255 -> clamp -> exchange
            #pragma unroll
            for (int nf = 0; nf < 2; nf++) {
                int col = n0 + nf * 16 + lr;
                float bv = pz_b3[col];
                #pragma unroll
                for (int r = 0; r < 4; r++) {
                    int row = l4 + r;
                    float zls = fminf(fmaxf(acc3[nf][r] + bv, -5.f), 2.f);
                    sm.zlsx[row * LDZX + (col - 128)] = zls;
                }
            }
        }
        __syncthreads();
        if (wv < 4) {    // z_mean cols 0..127 -> z_new (LDS+vt only), lq partial
            float rowsum[4] = {};
            #pragma unroll
            for (int nf = 0; nf < 2; nf++) {
                int d = n0 + nf * 16 + lr;
                float bv = pz_b3[d];
                #pragma unroll
                for (int r = 0; r < 4; r++) {
                    int row = l4 + r;
                    float zm = acc3[nf][r] + bv;
                    float zls = sm.zlsx[row * LDZX + d];
                    float e = eps_t[(size_t)(p0 + row) * dL + d];
                    float zn = zm + e * expf(zls);
                    short hi, lo;
                    split2(zn, hi, lo);
                    sm.e2hi[row * LDE + d] = hi;
                    sm.e2lo[row * LDE + d] = lo;
                    rowsum[r] += -0.5f * e * e - zls;
                }
            }
            #pragma unroll
            for (int o = 1; o < 16; o <<= 1)
                #pragma unroll
                for (int j = 0; j < 4; j++)
                    rowsum[j] += __shfl_xor(rowsum[j], o);
            if (lr == 0) {
                #pragma unroll
                for (int j = 0; j < 4; j++)
                    sm.lqp[wv * BLK + l4 + j] = rowsum[j];
            }
        }
    }
    __syncthreads();

    // ---- P3b: coalesced vt scatter of z_new split (2048 items) ----
    #pragma unroll
    for (int it = 0; it < 4; it++) {
        int idx = it * 512 + tid;
        int d = idx >> 4, row = idx & 15;
        vthi[((size_t)b * 144 + d) * 512 + i0 + row] = sm.e2hi[row * LDE + d];
        vtlo[((size_t)b * 144 + d) * 512 + i0 + row] = sm.e2lo[row * LDE + d];
    }

    // ---- P4: rlog8 = HR @ pr_w2 + b  (32 threads/particle) ----
    {
        int p = tid >> 5, s = tid & 31;
        float a8[8] = {};
        for (int kk = s * 8; kk < s * 8 + 8; kk++) {
            float hv = h2f(sm.actAhi[p * LDA + 256 + kk]) +
                       h2f(sm.actAlo[p * LDA + 256 + kk]);
            #pragma unroll
            for (int r = 0; r < 8; r++) a8[r] = fmaf(hv, pr_w2[kk * 8 + r], a8[r]);
        }
        #pragma unroll
        for (int o = 1; o < 32; o <<= 1)
            #pragma unroll
            for (int r = 0; r < 8; r++) a8[r] += __shfl_xor(a8[r], o);
        if (s == 0) {
            #pragma unroll
            for (int r = 0; r < 8; r++) {
                float v = a8[r] + pr_b2[r];
                sm.rlogL[p * 8 + r] = v;
                short hi, lo;
                split2(v, hi, lo);
                vthi[((size_t)b * 144 + 128 + r) * 512 + i0 + p] = hi;
                vtlo[((size_t)b * 144 + 128 + r) * 512 + i0 + p] = lo;
            }
        }
    }
    __syncthreads();

    // ---- P5: E1 = silu([h | z_new] @ oe_w1_perm) -> actA cols 0-255 ----
    {
        f32x4 acc5[2];
        acc5[0] = f32x4{0.f, 0.f, 0.f, 0.f};
        acc5[1] = f32x4{0.f, 0.f, 0.f, 0.f};
        int n0 = wv * 32;
        gemm_lds1<2, 0, 256, 384>(sm.hhhi, sm.hhlo, 0, 0, w_oe1h, w_oe1l, n0, lr, lk, acc5);
        gemm_lds1<2, 256, 384, 384>(sm.e2hi, sm.e2lo, LDE, 256, w_oe1h, w_oe1l, n0, lr, lk, acc5);
        __syncthreads();   // e2 reads done before P6 epi overwrites e2
        epi_silu1<2>(acc5, oe_b1 + n0, sm.actAhi, sm.actAlo, LDA, n0, lr, l4);
    }
    __syncthreads();

    // ---- P6: E2 = silu(E1 @ oe_w2) -> e2 buf ----
    {
        f32x4 acc6[1];
        acc6[0] = f32x4{0.f, 0.f, 0.f, 0.f};
        int n0 = wv * 16;
        gemm_lds1<1, 0, 256, 256>(sm.actAhi, sm.actAlo, LDA, 0, w_oe2h, w_oe2l, n0, lr, lk, acc6);
        __syncthreads();
        epi_silu1<1>(acc6, oe_b2 + n0, sm.e2hi, sm.e2lo, LDE, n0, lr, l4);
    }
    __syncthreads();

    // ---- P7: log_w = ll - log_q  (32 threads/particle) ----
    {
        int p = tid >> 5, s = tid & 31;
        float q0 = 0.f, q1 = 0.f;
        for (int k = s * 4; k < s * 4 + 4; k++) {
            float e = h2f(sm.e2hi[p * LDE + k]) + h2f(sm.e2lo[p * LDE + k]);
            q0 = fmaf(e, oe_w3[2 * k], q0);
            q1 = fmaf(e, oe_w3[2 * k + 1], q1);
        }
        #pragma unroll
        for (int o = 1; o < 32; o <<= 1) {
            q0 += __shfl_xor(q0, o);
            q1 += __shfl_xor(q1, o);
        }
        if (s == 0) {
            float pred = q0 + oe_b3[0];
            float lsb  = q1 + oe_b3[1];
            float rv[8], m = 0.f;
            #pragma unroll
            for (int r = 0; r < 8; r++) {
                rv[r] = sm.rlogL[p * 8 + r];
                m = fmaxf(m, rv[r]);
            }
            float denom = (Kt - 8) * expf(-m);
            #pragma unroll
            for (int r = 0; r < 8; r++) denom += expf(rv[r] - m);
            float sdot = 0.f;
            #pragma unroll
            for (int r = 0; r < 8; r++)
                sdot += (expf(rv[r] - m) / denom) * softplusf(los[r]);
            float sigma = fminf(fmaxf(softplusf(lsb) * sdot, 0.1f), 5.f);
            float y = obs_t[b];
            float dd = (y - pred) / sigma;
            float ll = -0.5f * dd * dd - logf(sigma) - 0.5f * LOG2PI;
            float lq = sm.lqp[p] + sm.lqp[BLK + p] + sm.lqp[2 * BLK + p]
                     + sm.lqp[3 * BLK + p] - dL * 0.5f * LOG2PI;
            log_w[p0 + p] = ll - lq;
        }
    }
}

// ---------------------------------------------------------------------------
// kT: weight convert+transpose+split with out stride/offset
// ---------------------------------------------------------------------------
__global__ __launch_bounds__(256) void kT(
    const float* __restrict__ in, short* __restrict__ oh, short* __restrict__ ol,
    int K, int N, int ostride, int ooff)
{
    int idx = blockIdx.x * 256 + threadIdx.x;
    if (idx < K * N) {
        int n = idx / K, k = idx % K;
        short hi, lo;
        split2(in[(size_t)k * N + n], hi, lo);
        oh[(size_t)n * ostride + ooff + k] = hi;
        ol[(size_t)n * ostride + ooff + k] = lo;
    }
}

// ---------------------------------------------------------------------------
// k11x: blocks < P/4: per-row softmax((log_w+g)/TEMP) -> split A planes +
// zero rl cols 8-17. Last 4 blocks: per-batch softmax(log_w) -> Amean.
// ---------------------------------------------------------------------------
__global__ __launch_bounds__(256) void k11x(
    const float* __restrict__ log_w, const float* __restrict__ u_t,
    short* __restrict__ Ahi, short* __restrict__ Alo,
    short* __restrict__ Ameanhi, short* __restrict__ Ameanlo,
    float* __restrict__ rl)
{
    int wave = threadIdx.x >> 6, lane = threadIdx.x & 63;
    if (blockIdx.x < P / 4) {
        int row = blockIdx.x * 4 + wave;
        int b = row >> 9;
        float q[8], m = -1e30f;
        #pragma unroll
        for (int jj = 0; jj < 8; jj++) {
            int j = jj * 64 + lane;
            float u = u_t[(size_t)row * Nn + j];
            float g = -logf(-logf(u + 1e-10f) + 1e-10f);
            q[jj] = (log_w[b * Nn + j] + g) * 2.0f;
            m = fmaxf(m, q[jj]);
        }
        #pragma unroll
        for (int o = 1; o < 64; o <<= 1) m = fmaxf(m, __shfl_xor(m, o));
        float e[8], s = 0.f;
        #pragma unroll
        for (int jj = 0; jj < 8; jj++) { e[jj] = expf(q[jj] - m); s += e[jj]; }
        #pragma unroll
        for (int o = 1; o < 64; o <<= 1) s += __shfl_xor(s, o);
        float inv = 1.f / s;
        #pragma unroll
        for (int jj = 0; jj < 8; jj++) {
            short hi, lo;
            split2(e[jj] * inv, hi, lo);
            Ahi[(size_t)row * Nn + jj * 64 + lane] = hi;
            Alo[(size_t)row * Nn + jj * 64 + lane] = lo;
        }
        if (lane < 10) rl[row * Kt + 8 + lane] = 0.f;
    } else {
        // batch-mean weights: b in 0..15, one wave per batch
        int b = (blockIdx.x - P / 4) * 4 + wave;
        float q[8], m = -1e30f;
        #pragma unroll
        for (int jj = 0; jj < 8; jj++) {
            q[jj] = log_w[b * Nn + jj * 64 + lane];
            m = fmaxf(m, q[jj]);
        }
        #pragma unroll
        for (int o = 1; o < 64; o <<= 1) m = fmaxf(m, __shfl_xor(m, o));
        float e[8], s = 0.f;
        #pragma unroll
        for (int jj = 0; jj < 8; jj++) { e[jj] = expf(q[jj] - m); s += e[jj]; }
        #pragma unroll
        for (int o = 1; o < 64; o <<= 1) s += __shfl_xor(s, o);
        float inv = 1.f / s;
        #pragma unroll
        for (int jj = 0; jj < 8; jj++) {
            short hi, lo;
            split2(e[jj] * inv, hi, lo);
            Ameanhi[(size_t)b * Nn + jj * 64 + lane] = hi;
            Ameanlo[(size_t)b * Nn + jj * 64 + lane] = lo;
        }
    }
}

// ---------------------------------------------------------------------------
// k12x: resample split MFMA GEMM per batch: C[512x144] = A @ V (y<8) +
// weighted-mean row via Amean (y==8: 16-row tile, row 0 only).
// grid (16, 9, 3); block 256.
// ---------------------------------------------------------------------------
__global__ __launch_bounds__(256) void k12x(
    const short* __restrict__ Ahi, const short* __restrict__ Alo,
    const short* __restrict__ Ameanhi, const short* __restrict__ Ameanlo,
    const short* __restrict__ vthi, const short* __restrict__ vtlo,
    float* __restrict__ z, float* __restrict__ rl, float* __restrict__ out_t)
{
    int tid = threadIdx.x;
    int w = tid >> 6, l = tid & 63;
    int lr = l & 15, lk = (l >> 4) * 8;
    int b = blockIdx.x;
    int n0 = blockIdx.z * 48;
    size_t voff = ((size_t)b * 144 + n0 + lr) * 512 + lk;

    if (blockIdx.y == 8) {
        // mean row: A row 0 = softmax(log_w[b]), rows 1-15 zero
        if (w != 0) return;
        f32x4 acc[3];
        #pragma unroll
        for (int nf = 0; nf < 3; nf++) acc[nf] = f32x4{0.f, 0.f, 0.f, 0.f};
        for (int k0 = 0; k0 < 512; k0 += 32) {
            f16x8 ah, al;
            #pragma unroll
            for (int j = 0; j < 8; j++) { ah[j] = (_Float16)0.f; al[j] = (_Float16)0.f; }
            if (lr == 0) {
                ah = *reinterpret_cast<const f16x8*>(Ameanhi + (size_t)b * Nn + k0 + lk);
                al = *reinterpret_cast<const f16x8*>(Ameanlo + (size_t)b * Nn + k0 + lk);
            }
            #pragma unroll
            for (int nf = 0; nf < 3; nf++) {
                size_t bo = voff + (size_t)nf * 16 * 512 + k0;
                f16x8 bh = *reinterpret_cast<const f16x8*>(vthi + bo);
                f16x8 bl = *reinterpret_cast<const f16x8*>(vtlo + bo);
                acc[nf] = mfma16(ah, bh, acc[nf]);
                acc[nf] = mfma16(ah, bl, acc[nf]);
                acc[nf] = mfma16(al, bh, acc[nf]);
            }
        }
        if ((l >> 4) == 0) {   // D row 0 lives in lanes 0-15, reg 0
            #pragma unroll
            for (int nf = 0; nf < 3; nf++) {
                int col = n0 + nf * 16 + lr;
                if (col < 128) out_t[b * dL + col] = acc[nf][0];
            }
        }
        return;
    }

    int m0 = blockIdx.y * 64 + w * 16;
    size_t aoff = ((size_t)(b * 512 + m0 + lr)) * 512 + lk;
    f32x4 acc[3];
    #pragma unroll
    for (int nf = 0; nf < 3; nf++) acc[nf] = f32x4{0.f, 0.f, 0.f, 0.f};
    for (int k0 = 0; k0 < 512; k0 += 32) {
        f16x8 ah = *reinterpret_cast<const f16x8*>(Ahi + aoff + k0);
        f16x8 al = *reinterpret_cast<const f16x8*>(Alo + aoff + k0);
        #pragma unroll
        for (int nf = 0; nf < 3; nf++) {
            size_t bo = voff + (size_t)nf * 16 * 512 + k0;
            f16x8 bh = *reinterpret_cast<const f16x8*>(vthi + bo);
            f16x8 bl = *reinterpret_cast<const f16x8*>(vtlo + bo);
            acc[nf] = mfma16(ah, bh, acc[nf]);
            acc[nf] = mfma16(ah, bl, acc[nf]);
            acc[nf] = mfma16(al, bh, acc[nf]);
        }
    }
    int orow = (l >> 4) * 4;
    #pragma unroll
    for (int nf = 0; nf < 3; nf++) {
        int col = n0 + nf * 16 + lr;
        #pragma unroll
        for (int r = 0; r < 4; r++) {
            int gp = b * 512 + m0 + orow + r;
            float v = acc[nf][r];
            if (col < 128) z[(size_t)gp * dL + col] = v;
            else if (col < 136) rl[gp * Kt + (col - 128)] = v;
        }
    }
}

// ---------------------------------------------------------------------------
extern "C" void kernel_launch(void* const* d_in, const int* in_sizes, int n_in,
                              void* d_out, int out_size, void* d_ws, size_t ws_size,
                              hipStream_t stream)
{
    const float* obs      = (const float*)d_in[0];
    const float* h_seq    = (const float*)d_in[1];
    const float* z0       = (const float*)d_in[2];
    const float* rl0      = (const float*)d_in[3];
    const float* eps      = (const float*)d_in[4];
    const float* gum      = (const float*)d_in[5];
    const float* pe_emb   = (const float*)d_in[6];
    const float* pz_w1    = (const float*)d_in[7];
    const float* pz_b1    = (const float*)d_in[8];
    const float* pz_w2    = (const float*)d_in[9];
    const float* pz_b2    = (const float*)d_in[10];
    const float* pz_w3    = (const float*)d_in[11];
    const float* pz_b3    = (const float*)d_in[12];
    const float* pr_w1    = (const float*)d_in[13];
    const float* pr_b1    = (const float*)d_in[14];
    const float* pr_w2    = (const float*)d_in[15];
    const float* pr_b2    = (const float*)d_in[16];
    const float* oe_w1    = (const float*)d_in[17];
    const float* oe_b1    = (const float*)d_in[18];
    const float* oe_w2    = (const float*)d_in[19];
    const float* oe_b2    = (const float*)d_in[20];
    const float* oe_w3    = (const float*)d_in[21];
    const float* oe_b3    = (const float*)d_in[22];
    const float* los      = (const float*)d_in[23];
    float* out = (float*)d_out;

    // workspace layout
    char* base = (char*)d_ws;
    float* z      = (float*)base;  base += (size_t)P * dL * 4;
    float* rl     = (float*)base;  base += (size_t)P * Kt * 4;
    float* log_w  = (float*)base;  base += (size_t)P * 4;
    short* vthi   = (short*)base;  base += (size_t)16 * 144 * 512 * 2;
    short* vtlo   = (short*)base;  base += (size_t)16 * 144 * 512 * 2;
    short* Ahi    = (short*)base;  base += (size_t)P * 512 * 2;
    short* Alo    = (short*)base;  base += (size_t)P * 512 * 2;
    short* Amhi   = (short*)base;  base += (size_t)16 * 512 * 2;
    short* Amlo   = (short*)base;  base += (size_t)16 * 512 * 2;
    short* w_l1h  = (short*)base;  base += (size_t)512 * 416 * 2;
    short* w_l1l  = (short*)base;  base += (size_t)512 * 416 * 2;
    short* w_pz2h = (short*)base;  base += (size_t)256 * 256 * 2;
    short* w_pz2l = (short*)base;  base += (size_t)256 * 256 * 2;
    short* w_pz3h = (short*)base;  base += (size_t)256 * 256 * 2;
    short* w_pz3l = (short*)base;  base += (size_t)256 * 256 * 2;
    short* w_oe1h = (short*)base;  base += (size_t)256 * 384 * 2;
    short* w_oe1l = (short*)base;  base += (size_t)256 * 384 * 2;
    short* w_oe2h = (short*)base;  base += (size_t)128 * 256 * 2;
    short* w_oe2l = (short*)base;  base += (size_t)128 * 256 * 2;

    // weight prep: transpose + split (layer1 concat; oe1 row-permuted [h|z])
    kT<<<(416 * 256 + 255) / 256, 256, 0, stream>>>(pz_w1, w_l1h, w_l1l, 416, 256, 416, 0);
    kT<<<(416 * 256 + 255) / 256, 256, 0, stream>>>(
        pr_w1, w_l1h + (size_t)256 * 416, w_l1l + (size_t)256 * 416, 416, 256, 416, 0);
    kT<<<(256 * 256 + 255) / 256, 256, 0, stream>>>(pz_w2, w_pz2h, w_pz2l, 256, 256, 256, 0);
    kT<<<(256 * 256 + 255) / 256, 256, 0, stream>>>(pz_w3, w_pz3h, w_pz3l, 256, 256, 256, 0);
    kT<<<(256 * 256 + 255) / 256, 256, 0, stream>>>(
        oe_w1 + (size_t)128 * 256, w_oe1h, w_oe1l, 256, 256, 384, 0);     // h rows
    kT<<<(128 * 256 + 255) / 256, 256, 0, stream>>>(
        oe_w1, w_oe1h, w_oe1l, 128, 256, 384, 256);                        // z rows
    kT<<<(256 * 128 + 255) / 256, 256, 0, stream>>>(oe_w2, w_oe2h, w_oe2l, 256, 128, 256, 0);

    // init carries
    (void)hipMemcpyAsync(z, z0, (size_t)P * dL * sizeof(float),
                         hipMemcpyDeviceToDevice, stream);
    (void)hipMemcpyAsync(rl, rl0, (size_t)P * Kt * sizeof(float),
                         hipMemcpyDeviceToDevice, stream);

    for (int t = 0; t < Tt; t++) {
        const float* h_t   = h_seq + (size_t)t * Bb * dM;
        const float* obs_t = obs + (size_t)t * Bb;
        const float* eps_t = eps + (size_t)t * P * dL;
        const float* u_t   = gum + (size_t)t * P * Nn;
        float* out_t = out + (size_t)t * Bb * dL;

        mega<<<P / BLK, 512, 0, stream>>>(
            z, rl, h_t, pe_emb, eps_t, obs_t,
            w_l1h, w_l1l, w_pz2h, w_pz2l, w_pz3h, w_pz3l,
            w_oe1h, w_oe1l, w_oe2h, w_oe2l,
            pz_b1, pr_b1, pz_b2, pz_b3, oe_b1, oe_b2,
            pr_w2, pr_b2, oe_w3, oe_b3, los,
            log_w, vthi, vtlo);
        k11x<<<P / 4 + 4, 256, 0, stream>>>(log_w, u_t, Ahi, Alo,
                                            Amhi, Amlo, rl);
        k12x<<<dim3(16, 9, 3), 256, 0, stream>>>(Ahi, Alo, Amhi, Amlo,
                                                 vthi, vtlo, z, rl, out_t);
    }
}

// Round 18
// 2006.589 us; speedup vs baseline: 1.2601x; 1.2601x over previous
//
#include <hip/hip_runtime.h>
#include <hip/hip_bf16.h>
#include <math.h>

#define LOG2PI 1.8378770664093453f

// Problem dims
constexpr int Bb = 16, Nn = 512, Tt = 16;
constexpr int dL = 128, dM = 256, dE = 32, Kt = 18;
constexpr int P = Bb * Nn;          // 8192 particles
constexpr int BLK = 32;             // particles per mega-block
// LDS row strides (in elements)
constexpr int LDA = 520;            // actA: 512 cols (H1|HR, later E1)
constexpr int LDB = 264;            // actB: 256 cols (H2)
constexpr int LDE = 136;            // e2/znew: 128 cols
constexpr int LDZX = 132;           // zls exchange (f32)
constexpr int LDR = 40;             // remb: 32 cols

typedef __attribute__((ext_vector_type(8))) _Float16 f16x8;
typedef __attribute__((ext_vector_type(4))) float f32x4;

__device__ __forceinline__ float siluf(float x) { return x / (1.f + expf(-x)); }
__device__ __forceinline__ float softplusf(float x) {
    return (x > 20.f) ? x : log1pf(expf(x));
}
__device__ __forceinline__ short f2h(float x) {
    _Float16 h = (_Float16)x;
    short s;
    __builtin_memcpy(&s, &h, 2);
    return s;
}
__device__ __forceinline__ float h2f(short s) {
    _Float16 h;
    __builtin_memcpy(&h, &s, 2);
    return (float)h;
}
__device__ __forceinline__ void split2(float x, short& hi, short& lo) {
    hi = f2h(x);
    lo = f2h(x - h2f(hi));
}
__device__ __forceinline__ f32x4 mfma16(f16x8 a, f16x8 b, f32x4 c) {
    return __builtin_amdgcn_mfma_f32_16x16x32_f16(a, b, c, 0, 0, 0);
}

// ---------------------------------------------------------------------------
// B-fragment loads + 3-term split MFMA for one k-step (wave owns 2 m-frags)
// ---------------------------------------------------------------------------
template<int NF>
__device__ __forceinline__ void mfma_bn(
    const f16x8 (&ah)[2], const f16x8 (&al)[2],
    const short* __restrict__ Whi, const short* __restrict__ Wlo,
    int Kw, int k0, int n0, int lr, int lk, f32x4 (&acc)[2][NF])
{
    #pragma unroll
    for (int nf = 0; nf < NF; nf++) {
        size_t bo = (size_t)(n0 + nf * 16 + lr) * Kw + k0 + lk;
        f16x8 bh = *reinterpret_cast<const f16x8*>(Whi + bo);
        f16x8 bl = *reinterpret_cast<const f16x8*>(Wlo + bo);
        #pragma unroll
        for (int mf = 0; mf < 2; mf++) {
            acc[mf][nf] = mfma16(ah[mf], bh, acc[mf][nf]);
            acc[mf][nf] = mfma16(ah[mf], bl, acc[mf][nf]);
            acc[mf][nf] = mfma16(al[mf], bh, acc[mf][nf]);
        }
    }
}

// GEMM k-range with A from LDS split planes (ldA=0 -> broadcast row, e.g. h)
template<int NF, int KB, int KE, int KW>
__device__ __forceinline__ void gemm_lds(
    const short* lAhi, const short* lAlo, int ldA, int akoff,
    const short* __restrict__ Whi, const short* __restrict__ Wlo,
    int n0, int lr, int lk, f32x4 (&acc)[2][NF])
{
    #pragma unroll 2
    for (int k0 = KB; k0 < KE; k0 += 32) {
        f16x8 ah[2], al[2];
        #pragma unroll
        for (int mf = 0; mf < 2; mf++) {
            int ao = (mf * 16 + lr) * ldA + (k0 - akoff) + lk;
            ah[mf] = *reinterpret_cast<const f16x8*>(lAhi + ao);
            al[mf] = *reinterpret_cast<const f16x8*>(lAlo + ao);
        }
        mfma_bn<NF>(ah, al, Whi, Wlo, KW, k0, n0, lr, lk, acc);
    }
}

// silu + split + store C-frags to LDS split buffer
template<int NF>
__device__ __forceinline__ void epi_silu(
    f32x4 (&acc)[2][NF], const float* biasw,
    short* outHi, short* outLo, int ldOut, int outBase, int lr, int l4)
{
    #pragma unroll
    for (int nf = 0; nf < NF; nf++) {
        float bv = biasw[nf * 16 + lr];
        #pragma unroll
        for (int mf = 0; mf < 2; mf++) {
            #pragma unroll
            for (int r = 0; r < 4; r++) {
                int row = mf * 16 + l4 + r;
                int col = outBase + nf * 16 + lr;
                float sv = siluf(acc[mf][nf][r] + bv);
                short hi, lo;
                split2(sv, hi, lo);
                outHi[row * ldOut + col] = hi;
                outLo[row * ldOut + col] = lo;
            }
        }
    }
}

struct SMem {
    short actAhi[BLK * LDA], actAlo[BLK * LDA];
    short actBhi[BLK * LDB], actBlo[BLK * LDB];
    short e2hi[BLK * LDE], e2lo[BLK * LDE];    // z_new split, then E2
    short hhhi[256], hhlo[256];
    short rembhi[BLK * LDR], remblo[BLK * LDR];
    float zlsx[BLK * LDZX];
    float peL[256];
    float probs[BLK * 8];
    float rlogL[BLK * 8];
    float lqp[4 * BLK];
};

// ---------------------------------------------------------------------------
// MEGA: per-step fused per-particle chain. 256 blocks x 512 thr (8 waves),
// 32 particles per block, 2 waves/SIMD. Wave owns 2 m-frags + 1 n-slice.
// (r13 structure; 3 address-disjoint barriers removed)
// ---------------------------------------------------------------------------
__global__ __launch_bounds__(512) void mega(
    const float* __restrict__ zc, const float* __restrict__ rl,
    const float* __restrict__ h_t, const float* __restrict__ pe_emb,
    const float* __restrict__ eps_t, const float* __restrict__ obs_t,
    const short* __restrict__ w_l1h, const short* __restrict__ w_l1l,
    const short* __restrict__ w_pz2h, const short* __restrict__ w_pz2l,
    const short* __restrict__ w_pz3h, const short* __restrict__ w_pz3l,
    const short* __restrict__ w_oe1h, const short* __restrict__ w_oe1l,
    const short* __restrict__ w_oe2h, const short* __restrict__ w_oe2l,
    const float* __restrict__ pz_b1, const float* __restrict__ pr_b1,
    const float* __restrict__ pz_b2, const float* __restrict__ pz_b3,
    const float* __restrict__ oe_b1, const float* __restrict__ oe_b2,
    const float* __restrict__ pr_w2, const float* __restrict__ pr_b2,
    const float* __restrict__ oe_w3, const float* __restrict__ oe_b3,
    const float* __restrict__ los,
    float* __restrict__ log_w,
    short* __restrict__ vthi, short* __restrict__ vtlo)
{
    __shared__ SMem sm;
    const int tid = threadIdx.x;
    const int wv = tid >> 6, l = tid & 63;
    const int lr = l & 15, lk = (l >> 4) * 8, l4 = (l >> 4) * 4;
    const int p0 = blockIdx.x * BLK;
    const int b = p0 >> 9;
    const int i0 = p0 & 511;

    // ---- P0: h broadcast, pe_emb, regime probs, vt pad zero ----
    {
        if (tid < 256) {
            const float* hb = h_t + b * dM;
            short hi, lo;
            split2(hb[tid], hi, lo);
            sm.hhhi[tid] = hi; sm.hhlo[tid] = lo;
            sm.peL[tid] = pe_emb[tid];
        } else {
            // vt pad cols 136-143 zero (256 items)
            int q = tid - 256;
            int pp = q >> 3, cc = q & 7;
            vthi[((size_t)b * 144 + 136 + cc) * 512 + i0 + pp] = 0;
            vtlo[((size_t)b * 144 + 136 + cc) * 512 + i0 + pp] = 0;
        }
        if (tid < BLK) {
            int p = tid;
            float v[Kt], m = -1e30f;
            #pragma unroll
            for (int k = 0; k < Kt; k++) {
                v[k] = rl[(size_t)(p0 + p) * Kt + k];
                m = fmaxf(m, v[k]);
            }
            float denom = 0.f;
            #pragma unroll
            for (int k = 0; k < Kt; k++) denom += expf(v[k] - m);
            #pragma unroll
            for (int k = 0; k < 8; k++)
                sm.probs[p * 8 + k] = expf(v[k] - m) / denom;
        }
    }
    __syncthreads();
    // remb = probs @ pe_emb[:8]  (split into LDS) — 1024 items / 512 thr
    {
        #pragma unroll
        for (int it = 0; it < 2; it++) {
            int idx = it * 512 + tid;
            int p = idx >> 5, d = idx & 31;
            float acc = 0.f;
            #pragma unroll
            for (int kk = 0; kk < 8; kk++)
                acc = fmaf(sm.probs[p * 8 + kk], sm.peL[kk * 32 + d], acc);
            short hi, lo;
            split2(acc, hi, lo);
            sm.rembhi[p * LDR + d] = hi;
            sm.remblo[p * LDR + d] = lo;
        }
    }
    __syncthreads();

    // ---- P1: layer1 [H1|HR] = silu(X @ [pz_w1|pr_w1]) ; X composed on the fly
    {
        f32x4 acc1[2][4];
        #pragma unroll
        for (int mf = 0; mf < 2; mf++)
            #pragma unroll
            for (int nf = 0; nf < 4; nf++) acc1[mf][nf] = f32x4{0.f, 0.f, 0.f, 0.f};
        int n0 = wv * 64;
        // k 0..255: h (broadcast rows)
        gemm_lds<4, 0, 256, 416>(sm.hhhi, sm.hhlo, 0, 0, w_l1h, w_l1l, n0, lr, lk, acc1);
        // k 256..383: z carry from global f32, split on the fly
        #pragma unroll 2
        for (int k0 = 256; k0 < 384; k0 += 32) {
            f16x8 ah[2], al[2];
            #pragma unroll
            for (int mf = 0; mf < 2; mf++) {
                const float* zr = zc + (size_t)(p0 + mf * 16 + lr) * dL + (k0 - 256) + lk;
                #pragma unroll
                for (int j = 0; j < 8; j++) {
                    float zv = zr[j];
                    _Float16 h = (_Float16)zv;
                    ah[mf][j] = h;
                    al[mf][j] = (_Float16)(zv - (float)h);
                }
            }
            mfma_bn<4>(ah, al, w_l1h, w_l1l, 416, k0, n0, lr, lk, acc1);
        }
        // k 384..415: remb
        gemm_lds<4, 384, 416, 416>(sm.rembhi, sm.remblo, LDR, 384, w_l1h, w_l1l, n0, lr, lk, acc1);
        const float* biasw = (n0 < 256) ? (pz_b1 + n0) : (pr_b1 + (n0 - 256));
        epi_silu<4>(acc1, biasw, sm.actAhi, sm.actAlo, LDA, n0, lr, l4);
    }
    __syncthreads();

    // ---- P2: H2 = silu(H1 @ pz_w2) ----
    {
        f32x4 acc2[2][2];
        #pragma unroll
        for (int mf = 0; mf < 2; mf++)
            #pragma unroll
            for (int nf = 0; nf < 2; nf++) acc2[mf][nf] = f32x4{0.f, 0.f, 0.f, 0.f};
        int n0 = wv * 32;
        gemm_lds<2, 0, 256, 256>(sm.actAhi, sm.actAlo, LDA, 0, w_pz2h, w_pz2l, n0, lr, lk, acc2);
        epi_silu<2>(acc2, pz_b2 + n0, sm.actBhi, sm.actBlo, LDB, n0, lr, l4);
    }
    __syncthreads();

    // ---- P3: ZP = H2 @ pz_w3 (raw); z_new, log_q ----
    {
        f32x4 acc3[2][2];
        #pragma unroll
        for (int mf = 0; mf < 2; mf++)
            #pragma unroll
            for (int nf = 0; nf < 2; nf++) acc3[mf][nf] = f32x4{0.f, 0.f, 0.f, 0.f};
        int n0 = wv * 32;
        gemm_lds<2, 0, 256, 256>(sm.actBhi, sm.actBlo, LDB, 0, w_pz3h, w_pz3l, n0, lr, lk, acc3);
        if (wv >= 4) {   // z_log_std cols 128..255 -> clamp -> exchange
            #pragma unroll
            for (int nf = 0; nf < 2; nf++) {
                int col = n0 + nf * 16 + lr;
                float bv = pz_b3[col];
                #pragma unroll
                for (int mf = 0; mf < 2; mf++)
                    #pragma unroll
                    for (int r = 0; r < 4; r++) {
                        int row = mf * 16 + l4 + r;
                        float zls = fminf(fmaxf(acc3[mf][nf][r] + bv, -5.f), 2.f);
                        sm.zlsx[row * LDZX + (col - 128)] = zls;
                    }
            }
        }
        __syncthreads();
        if (wv < 4) {    // z_mean cols 0..127 -> z_new (LDS+vt only), lq partial
            float rowsum[8] = {};
            #pragma unroll
            for (int nf = 0; nf < 2; nf++) {
                int d = n0 + nf * 16 + lr;
                float bv = pz_b3[d];
                #pragma unroll
                for (int mf = 0; mf < 2; mf++)
                    #pragma unroll
                    for (int r = 0; r < 4; r++) {
                        int row = mf * 16 + l4 + r;
                        float zm = acc3[mf][nf][r] + bv;
                        float zls = sm.zlsx[row * LDZX + d];
                        float e = eps_t[(size_t)(p0 + row) * dL + d];
                        float zn = zm + e * expf(zls);
                        short hi, lo;
                        split2(zn, hi, lo);
                        sm.e2hi[row * LDE + d] = hi;
                        sm.e2lo[row * LDE + d] = lo;
                        rowsum[mf * 4 + r] += -0.5f * e * e - zls;
                    }
            }
            #pragma unroll
            for (int o = 1; o < 16; o <<= 1)
                #pragma unroll
                for (int j = 0; j < 8; j++)
                    rowsum[j] += __shfl_xor(rowsum[j], o);
            if (lr == 0) {
                #pragma unroll
                for (int j = 0; j < 8; j++) {
                    int row = (j >> 2) * 16 + l4 + (j & 3);
                    sm.lqp[wv * BLK + row] = rowsum[j];
                }
            }
        }
    }
    __syncthreads();

    // ---- P3b: coalesced vt scatter of z_new split (4096 items) ----
    #pragma unroll
    for (int it = 0; it < 8; it++) {
        int idx = it * 512 + tid;
        int d = idx >> 5, row = idx & 31;
        vthi[((size_t)b * 144 + d) * 512 + i0 + row] = sm.e2hi[row * LDE + d];
        vtlo[((size_t)b * 144 + d) * 512 + i0 + row] = sm.e2lo[row * LDE + d];
    }

    // ---- P4: rlog8 = HR @ pr_w2 + b  (16 threads/particle) ----
    {
        int p = tid >> 4, s = tid & 15;
        float a8[8] = {};
        for (int kk = s * 16; kk < s * 16 + 16; kk++) {
            float hv = h2f(sm.actAhi[p * LDA + 256 + kk]) +
                       h2f(sm.actAlo[p * LDA + 256 + kk]);
            #pragma unroll
            for (int r = 0; r < 8; r++) a8[r] = fmaf(hv, pr_w2[kk * 8 + r], a8[r]);
        }
        #pragma unroll
        for (int o = 1; o < 16; o <<= 1)
            #pragma unroll
            for (int r = 0; r < 8; r++) a8[r] += __shfl_xor(a8[r], o);
        if (s == 0) {
            #pragma unroll
            for (int r = 0; r < 8; r++) {
                float v = a8[r] + pr_b2[r];
                sm.rlogL[p * 8 + r] = v;
                short hi, lo;
                split2(v, hi, lo);
                vthi[((size_t)b * 144 + 128 + r) * 512 + i0 + p] = hi;
                vtlo[((size_t)b * 144 + 128 + r) * 512 + i0 + p] = lo;
            }
        }
    }
    // NOTE: no barrier here — P4 reads actA cols 256-511; P5 writes cols 0-255
    // (disjoint); P5's gemm inputs (e2, hh) are stable since P3's barrier.

    // ---- P5: E1 = silu([h | z_new] @ oe_w1_perm) -> actA cols 0-255 ----
    {
        f32x4 acc5[2][2];
        #pragma unroll
        for (int mf = 0; mf < 2; mf++)
            #pragma unroll
            for (int nf = 0; nf < 2; nf++) acc5[mf][nf] = f32x4{0.f, 0.f, 0.f, 0.f};
        int n0 = wv * 32;
        gemm_lds<2, 0, 256, 384>(sm.hhhi, sm.hhlo, 0, 0, w_oe1h, w_oe1l, n0, lr, lk, acc5);
        gemm_lds<2, 256, 384, 384>(sm.e2hi, sm.e2lo, LDE, 256, w_oe1h, w_oe1l, n0, lr, lk, acc5);
        // epi writes actA cols 0-255; nothing reads actA cols 0-255 in P5
        epi_silu<2>(acc5, oe_b1 + n0, sm.actAhi, sm.actAlo, LDA, n0, lr, l4);
    }
    __syncthreads();

    // ---- P6: E2 = silu(E1 @ oe_w2) -> e2 buf ----
    {
        f32x4 acc6[2][1];
        #pragma unroll
        for (int mf = 0; mf < 2; mf++) acc6[mf][0] = f32x4{0.f, 0.f, 0.f, 0.f};
        int n0 = wv * 16;
        gemm_lds<1, 0, 256, 256>(sm.actAhi, sm.actAlo, LDA, 0, w_oe2h, w_oe2l, n0, lr, lk, acc6);
        // epi writes e2; this phase reads only actA (disjoint) -> no barrier
        epi_silu<1>(acc6, oe_b2 + n0, sm.e2hi, sm.e2lo, LDE, n0, lr, l4);
    }
    __syncthreads();

    // ---- P7: log_w = ll - log_q  (16 threads/particle) ----
    {
        int p = tid >> 4, s = tid & 15;
        float q0 = 0.f, q1 = 0.f;
        for (int k = s * 8; k < s * 8 + 8; k++) {
            float e = h2f(sm.e2hi[p * LDE + k]) + h2f(sm.e2lo[p * LDE + k]);
            q0 = fmaf(e, oe_w3[2 * k], q0);
            q1 = fmaf(e, oe_w3[2 * k + 1], q1);
        }
        #pragma unroll
        for (int o = 1; o < 16; o <<= 1) {
            q0 += __shfl_xor(q0, o);
            q1 += __shfl_xor(q1, o);
        }
        if (s == 0) {
            float pred = q0 + oe_b3[0];
            float lsb  = q1 + oe_b3[1];
            float rv[8], m = 0.f;
            #pragma unroll
            for (int r = 0; r < 8; r++) {
                rv[r] = sm.rlogL[p * 8 + r];
                m = fmaxf(m, rv[r]);
            }
            float denom = (Kt - 8) * expf(-m);
            #pragma unroll
            for (int r = 0; r < 8; r++) denom += expf(rv[r] - m);
            float sdot = 0.f;
            #pragma unroll
            for (int r = 0; r < 8; r++)
                sdot += (expf(rv[r] - m) / denom) * softplusf(los[r]);
            float sigma = fminf(fmaxf(softplusf(lsb) * sdot, 0.1f), 5.f);
            float y = obs_t[b];
            float dd = (y - pred) / sigma;
            float ll = -0.5f * dd * dd - logf(sigma) - 0.5f * LOG2PI;
            float lq = sm.lqp[p] + sm.lqp[BLK + p] + sm.lqp[2 * BLK + p]
                     + sm.lqp[3 * BLK + p] - dL * 0.5f * LOG2PI;
            log_w[p0 + p] = ll - lq;
        }
    }
}

// ---------------------------------------------------------------------------
// kT: weight convert+transpose+split with out stride/offset
// ---------------------------------------------------------------------------
__global__ __launch_bounds__(256) void kT(
    const float* __restrict__ in, short* __restrict__ oh, short* __restrict__ ol,
    int K, int N, int ostride, int ooff)
{
    int idx = blockIdx.x * 256 + threadIdx.x;
    if (idx < K * N) {
        int n = idx / K, k = idx % K;
        short hi, lo;
        split2(in[(size_t)k * N + n], hi, lo);
        oh[(size_t)n * ostride + ooff + k] = hi;
        ol[(size_t)n * ostride + ooff + k] = lo;
    }
}

// ---------------------------------------------------------------------------
// k11x: blocks < P/4: per-row softmax((log_w+g)/TEMP) -> split A planes +
// zero rl cols 8-17. Last 4 blocks: per-batch softmax(log_w) -> Amean.
// ---------------------------------------------------------------------------
__global__ __launch_bounds__(256) void k11x(
    const float* __restrict__ log_w, const float* __restrict__ u_t,
    short* __restrict__ Ahi, short* __restrict__ Alo,
    short* __restrict__ Ameanhi, short* __restrict__ Ameanlo,
    float* __restrict__ rl)
{
    int wave = threadIdx.x >> 6, lane = threadIdx.x & 63;
    if (blockIdx.x < P / 4) {
        int row = blockIdx.x * 4 + wave;
        int b = row >> 9;
        float q[8], m = -1e30f;
        #pragma unroll
        for (int jj = 0; jj < 8; jj++) {
            int j = jj * 64 + lane;
            float u = u_t[(size_t)row * Nn + j];
            float g = -logf(-logf(u + 1e-10f) + 1e-10f);
            q[jj] = (log_w[b * Nn + j] + g) * 2.0f;
            m = fmaxf(m, q[jj]);
        }
        #pragma unroll
        for (int o = 1; o < 64; o <<= 1) m = fmaxf(m, __shfl_xor(m, o));
        float e[8], s = 0.f;
        #pragma unroll
        for (int jj = 0; jj < 8; jj++) { e[jj] = expf(q[jj] - m); s += e[jj]; }
        #pragma unroll
        for (int o = 1; o < 64; o <<= 1) s += __shfl_xor(s, o);
        float inv = 1.f / s;
        #pragma unroll
        for (int jj = 0; jj < 8; jj++) {
            short hi, lo;
            split2(e[jj] * inv, hi, lo);
            Ahi[(size_t)row * Nn + jj * 64 + lane] = hi;
            Alo[(size_t)row * Nn + jj * 64 + lane] = lo;
        }
        if (lane < 10) rl[row * Kt + 8 + lane] = 0.f;
    } else {
        // batch-mean weights: b in 0..15, one wave per batch
        int b = (blockIdx.x - P / 4) * 4 + wave;
        float q[8], m = -1e30f;
        #pragma unroll
        for (int jj = 0; jj < 8; jj++) {
            q[jj] = log_w[b * Nn + jj * 64 + lane];
            m = fmaxf(m, q[jj]);
        }
        #pragma unroll
        for (int o = 1; o < 64; o <<= 1) m = fmaxf(m, __shfl_xor(m, o));
        float e[8], s = 0.f;
        #pragma unroll
        for (int jj = 0; jj < 8; jj++) { e[jj] = expf(q[jj] - m); s += e[jj]; }
        #pragma unroll
        for (int o = 1; o < 64; o <<= 1) s += __shfl_xor(s, o);
        float inv = 1.f / s;
        #pragma unroll
        for (int jj = 0; jj < 8; jj++) {
            short hi, lo;
            split2(e[jj] * inv, hi, lo);
            Ameanhi[(size_t)b * Nn + jj * 64 + lane] = hi;
            Ameanlo[(size_t)b * Nn + jj * 64 + lane] = lo;
        }
    }
}

// ---------------------------------------------------------------------------
// k12x: resample split MFMA GEMM per batch: C[512x144] = A @ V (y<8) +
// weighted-mean row via Amean (y==8: 16-row tile, row 0 only).
// grid (16, 9, 3); block 256.
// ---------------------------------------------------------------------------
__global__ __launch_bounds__(256) void k12x(
    const short* __restrict__ Ahi, const short* __restrict__ Alo,
    const short* __restrict__ Ameanhi, const short* __restrict__ Ameanlo,
    const short* __restrict__ vthi, const short* __restrict__ vtlo,
    float* __restrict__ z, float* __restrict__ rl, float* __restrict__ out_t)
{
    int tid = threadIdx.x;
    int w = tid >> 6, l = tid & 63;
    int lr = l & 15, lk = (l >> 4) * 8;
    int b = blockIdx.x;
    int n0 = blockIdx.z * 48;
    size_t voff = ((size_t)b * 144 + n0 + lr) * 512 + lk;

    if (blockIdx.y == 8) {
        // mean row: A row 0 = softmax(log_w[b]), rows 1-15 zero
        if (w != 0) return;
        f32x4 acc[3];
        #pragma unroll
        for (int nf = 0; nf < 3; nf++) acc[nf] = f32x4{0.f, 0.f, 0.f, 0.f};
        for (int k0 = 0; k0 < 512; k0 += 32) {
            f16x8 ah, al;
            #pragma unroll
            for (int j = 0; j < 8; j++) { ah[j] = (_Float16)0.f; al[j] = (_Float16)0.f; }
            if (lr == 0) {
                ah = *reinterpret_cast<const f16x8*>(Ameanhi + (size_t)b * Nn + k0 + lk);
                al = *reinterpret_cast<const f16x8*>(Ameanlo + (size_t)b * Nn + k0 + lk);
            }
            #pragma unroll
            for (int nf = 0; nf < 3; nf++) {
                size_t bo = voff + (size_t)nf * 16 * 512 + k0;
                f16x8 bh = *reinterpret_cast<const f16x8*>(vthi + bo);
                f16x8 bl = *reinterpret_cast<const f16x8*>(vtlo + bo);
                acc[nf] = mfma16(ah, bh, acc[nf]);
                acc[nf] = mfma16(ah, bl, acc[nf]);
                acc[nf] = mfma16(al, bh, acc[nf]);
            }
        }
        if ((l >> 4) == 0) {   // D row 0 lives in lanes 0-15, reg 0
            #pragma unroll
            for (int nf = 0; nf < 3; nf++) {
                int col = n0 + nf * 16 + lr;
                if (col < 128) out_t[b * dL + col] = acc[nf][0];
            }
        }
        return;
    }

    int m0 = blockIdx.y * 64 + w * 16;
    size_t aoff = ((size_t)(b * 512 + m0 + lr)) * 512 + lk;
    f32x4 acc[3];
    #pragma unroll
    for (int nf = 0; nf < 3; nf++) acc[nf] = f32x4{0.f, 0.f, 0.f, 0.f};
    for (int k0 = 0; k0 < 512; k0 += 32) {
        f16x8 ah = *reinterpret_cast<const f16x8*>(Ahi + aoff + k0);
        f16x8 al = *reinterpret_cast<const f16x8*>(Alo + aoff + k0);
        #pragma unroll
        for (int nf = 0; nf < 3; nf++) {
            size_t bo = voff + (size_t)nf * 16 * 512 + k0;
            f16x8 bh = *reinterpret_cast<const f16x8*>(vthi + bo);
            f16x8 bl = *reinterpret_cast<const f16x8*>(vtlo + bo);
            acc[nf] = mfma16(ah, bh, acc[nf]);
            acc[nf] = mfma16(ah, bl, acc[nf]);
            acc[nf] = mfma16(al, bh, acc[nf]);
        }
    }
    int orow = (l >> 4) * 4;
    #pragma unroll
    for (int nf = 0; nf < 3; nf++) {
        int col = n0 + nf * 16 + lr;
        #pragma unroll
        for (int r = 0; r < 4; r++) {
            int gp = b * 512 + m0 + orow + r;
            float v = acc[nf][r];
            if (col < 128) z[(size_t)gp * dL + col] = v;
            else if (col < 136) rl[gp * Kt + (col - 128)] = v;
        }
    }
}

// ---------------------------------------------------------------------------
extern "C" void kernel_launch(void* const* d_in, const int* in_sizes, int n_in,
                              void* d_out, int out_size, void* d_ws, size_t ws_size,
                              hipStream_t stream)
{
    const float* obs      = (const float*)d_in[0];
    const float* h_seq    = (const float*)d_in[1];
    const float* z0       = (const float*)d_in[2];
    const float* rl0      = (const float*)d_in[3];
    const float* eps      = (const float*)d_in[4];
    const float* gum      = (const float*)d_in[5];
    const float* pe_emb   = (const float*)d_in[6];
    const float* pz_w1    = (const float*)d_in[7];
    const float* pz_b1    = (const float*)d_in[8];
    const float* pz_w2    = (const float*)d_in[9];
    const float* pz_b2    = (const float*)d_in[10];
    const float* pz_w3    = (const float*)d_in[11];
    const float* pz_b3    = (const float*)d_in[12];
    const float* pr_w1    = (const float*)d_in[13];
    const float* pr_b1    = (const float*)d_in[14];
    const float* pr_w2    = (const float*)d_in[15];
    const float* pr_b2    = (const float*)d_in[16];
    const float* oe_w1    = (const float*)d_in[17];
    const float* oe_b1    = (const float*)d_in[18];
    const float* oe_w2    = (const float*)d_in[19];
    const float* oe_b2    = (const float*)d_in[20];
    const float* oe_w3    = (const float*)d_in[21];
    const float* oe_b3    = (const float*)d_in[22];
    const float* los      = (const float*)d_in[23];
    float* out = (float*)d_out;

    // workspace layout
    char* base = (char*)d_ws;
    float* z      = (float*)base;  base += (size_t)P * dL * 4;
    float* rl     = (float*)base;  base += (size_t)P * Kt * 4;
    float* log_w  = (float*)base;  base += (size_t)P * 4;
    short* vthi   = (short*)base;  base += (size_t)16 * 144 * 512 * 2;
    short* vtlo   = (short*)base;  base += (size_t)16 * 144 * 512 * 2;
    short* Ahi    = (short*)base;  base += (size_t)P * 512 * 2;
    short* Alo    = (short*)base;  base += (size_t)P * 512 * 2;
    short* Amhi   = (short*)base;  base += (size_t)16 * 512 * 2;
    short* Amlo   = (short*)base;  base += (size_t)16 * 512 * 2;
    short* w_l1h  = (short*)base;  base += (size_t)512 * 416 * 2;
    short* w_l1l  = (short*)base;  base += (size_t)512 * 416 * 2;
    short* w_pz2h = (short*)base;  base += (size_t)256 * 256 * 2;
    short* w_pz2l = (short*)base;  base += (size_t)256 * 256 * 2;
    short* w_pz3h = (short*)base;  base += (size_t)256 * 256 * 2;
    short* w_pz3l = (short*)base;  base += (size_t)256 * 256 * 2;
    short* w_oe1h = (short*)base;  base += (size_t)256 * 384 * 2;
    short* w_oe1l = (short*)base;  base += (size_t)256 * 384 * 2;
    short* w_oe2h = (short*)base;  base += (size_t)128 * 256 * 2;
    short* w_oe2l = (short*)base;  base += (size_t)128 * 256 * 2;

    // weight prep: transpose + split (layer1 concat; oe1 row-permuted [h|z])
    kT<<<(416 * 256 + 255) / 256, 256, 0, stream>>>(pz_w1, w_l1h, w_l1l, 416, 256, 416, 0);
    kT<<<(416 * 256 + 255) / 256, 256, 0, stream>>>(
        pr_w1, w_l1h + (size_t)256 * 416, w_l1l + (size_t)256 * 416, 416, 256, 416, 0);
    kT<<<(256 * 256 + 255) / 256, 256, 0, stream>>>(pz_w2, w_pz2h, w_pz2l, 256, 256, 256, 0);
    kT<<<(256 * 256 + 255) / 256, 256, 0, stream>>>(pz_w3, w_pz3h, w_pz3l, 256, 256, 256, 0);
    kT<<<(256 * 256 + 255) / 256, 256, 0, stream>>>(
        oe_w1 + (size_t)128 * 256, w_oe1h, w_oe1l, 256, 256, 384, 0);     // h rows
    kT<<<(128 * 256 + 255) / 256, 256, 0, stream>>>(
        oe_w1, w_oe1h, w_oe1l, 128, 256, 384, 256);                        // z rows
    kT<<<(256 * 128 + 255) / 256, 256, 0, stream>>>(oe_w2, w_oe2h, w_oe2l, 256, 128, 256, 0);

    // init carries
    (void)hipMemcpyAsync(z, z0, (size_t)P * dL * sizeof(float),
                         hipMemcpyDeviceToDevice, stream);
    (void)hipMemcpyAsync(rl, rl0, (size_t)P * Kt * sizeof(float),
                         hipMemcpyDeviceToDevice, stream);

    for (int t = 0; t < Tt; t++) {
        const float* h_t   = h_seq + (size_t)t * Bb * dM;
        const float* obs_t = obs + (size_t)t * Bb;
        const float* eps_t = eps + (size_t)t * P * dL;
        const float* u_t   = gum + (size_t)t * P * Nn;
        float* out_t = out + (size_t)t * Bb * dL;

        mega<<<P / BLK, 512, 0, stream>>>(
            z, rl, h_t, pe_emb, eps_t, obs_t,
            w_l1h, w_l1l, w_pz2h, w_pz2l, w_pz3h, w_pz3l,
            w_oe1h, w_oe1l, w_oe2h, w_oe2l,
            pz_b1, pr_b1, pz_b2, pz_b3, oe_b1, oe_b2,
            pr_w2, pr_b2, oe_w3, oe_b3, los,
            log_w, vthi, vtlo);
        k11x<<<P / 4 + 4, 256, 0, stream>>>(log_w, u_t, Ahi, Alo,
                                            Amhi, Amlo, rl);
        k12x<<<dim3(16, 9, 3), 256, 0, stream>>>(Ahi, Alo, Amhi, Amlo,
                                                 vthi, vtlo, z, rl, out_t);
    }
}